// Round 4
// baseline (637.701 us; speedup 1.0000x reference)
//
#include <hip/hip_runtime.h>

#define B_ 4
#define N_ 325
#define I_ 64
#define H_ 128
#define NODES (B_ * N_)
#define NZMAX 512

typedef unsigned short u16;
typedef unsigned int u32;

// Runtime input-dtype flag: 1 = fp32, 0 = bf16. Set by k_probe each launch.
__device__ int g_isf32;

// Module-scope scratch (allocated at .so load; fully rewritten every launch).
__device__ float g_h_lstm [NODES * H_];
__device__ float g_support[NODES * H_];
__device__ float g_h_graph[NODES * H_];
__device__ float g_s_buf  [NODES * H_];
__device__ float g_t_buf  [NODES * H_];

__device__ __forceinline__ float bf2f(u16 u) { return __uint_as_float(((u32)u) << 16); }
__device__ __forceinline__ u16 f2bf(float f) {
    u32 u = __float_as_uint(f);
    u += 0x7fffu + ((u >> 16) & 1u);   // round-to-nearest-even
    return (u16)(u >> 16);
}
__device__ __forceinline__ float ldin(const void* p, size_t i, int f32) {
    return f32 ? ((const float*)p)[i] : bf2f(((const u16*)p)[i]);
}
__device__ __forceinline__ void stout(void* p, size_t i, float v, int f32) {
    if (f32) ((float*)p)[i] = v; else ((u16*)p)[i] = f2bf(v);
}
__device__ __forceinline__ float sigm(float x) { return 1.f / (1.f + expf(-x)); }

// Probe adj[0,0] == 1.0 (self-loop guaranteed): fp32 stores 0x3F800000 in the
// first 4 bytes (low16 = 0x0000); bf16 stores 0x3F80 in the first 2 bytes.
__global__ void k_probe(const void* adj) {
    g_isf32 = ((((const u32*)adj)[0] & 0xFFFFu) != 0x3F80u) ? 1 : 0;
}

// ---------------------------------------------------------------------------
// K1: per-node LSTM cell + support = h_lstm @ gc_w.  One block per node.
// ---------------------------------------------------------------------------
__global__ __launch_bounds__(256) void k_lstm(
    const void* x, const void* h, const void* c,
    const void* W_ih, const void* W_hh, const void* b_ih, const void* b_hh,
    const void* gc_w, void* out)
{
    const int f32 = g_isf32;
    __shared__ float xh[I_ + H_];
    __shared__ float gates[4 * H_];
    __shared__ float hl[H_];
    __shared__ float spart[256];
    const int node = blockIdx.x;
    const int t = threadIdx.x;

    if (t < I_) xh[t] = ldin(x, (size_t)node * I_ + t, f32);
    if (t < H_) xh[I_ + t] = ldin(h, (size_t)node * H_ + t, f32);
    __syncthreads();

    for (int gg = 0; gg < 2; ++gg) {
        const int g = t + gg * 256;
        float acc = ldin(b_ih, g, f32) + ldin(b_hh, g, f32);
        for (int k = 0; k < I_; ++k)
            acc = fmaf(xh[k], ldin(W_ih, (size_t)g * I_ + k, f32), acc);
        for (int k = 0; k < H_; ++k)
            acc = fmaf(xh[I_ + k], ldin(W_hh, (size_t)g * H_ + k, f32), acc);
        gates[g] = acc;
    }
    __syncthreads();

    if (t < H_) {
        float ig = gates[t], fg = gates[H_ + t], gv = gates[2 * H_ + t], og = gates[3 * H_ + t];
        float cl = sigm(fg) * ldin(c, (size_t)node * H_ + t, f32) + sigm(ig) * tanhf(gv);
        float hv = sigm(og) * tanhf(cl);
        stout(out, (size_t)(NODES * H_) + (size_t)node * H_ + t, cl, f32);  // c_lstm
        g_h_lstm[node * H_ + t] = hv;
        hl[t] = hv;
    }
    __syncthreads();

    // support[o] = sum_k hl[k] * gc_w[k][o]; k-range split across the 2 halves
    const int o = t & (H_ - 1);
    const int half = t >> 7;
    float acc = 0.f;
    for (int k = half * 64; k < half * 64 + 64; ++k)
        acc = fmaf(hl[k], ldin(gc_w, (size_t)k * H_ + o, f32), acc);
    spart[t] = acc;
    __syncthreads();
    if (t < H_) g_support[node * H_ + t] = spart[t] + spart[t + H_];
}

// ---------------------------------------------------------------------------
// K2: sparse h_graph = adj @ support + gc_b ; s = h_graph @ Ws^T ; t = @ Wt^T
// ---------------------------------------------------------------------------
__global__ __launch_bounds__(256) void k_graph(
    const void* adj, const void* gc_b,
    const void* Ws_w, const void* Ws_b, const void* Wt_w, const void* Wt_b)
{
    const int f32 = g_isf32;
    __shared__ float hg[H_];
    __shared__ u16 nzi[NZMAX];
    __shared__ float nzv[NZMAX];
    __shared__ int cnt;
    const int node = blockIdx.x;
    const int b = node / N_;
    const int t = threadIdx.x;

    if (t == 0) cnt = 0;
    __syncthreads();
    for (int j = t; j < N_; j += 256) {
        float a = ldin(adj, (size_t)node * N_ + j, f32);
        if (a != 0.f) {
            int p = atomicAdd(&cnt, 1);
            if (p < NZMAX) { nzi[p] = (u16)j; nzv[p] = a; }
        }
    }
    __syncthreads();
    const int cn = min(cnt, NZMAX);

    if (t < H_) {
        float acc = ldin(gc_b, t, f32);
        for (int p = 0; p < cn; ++p)
            acc = fmaf(nzv[p], g_support[((size_t)b * N_ + nzi[p]) * H_ + t], acc);
        hg[t] = acc;
        g_h_graph[(size_t)node * H_ + t] = acc;
    }
    __syncthreads();

    // s (threads 0..127) and t (threads 128..255) projections: W[o][h] rows
    const int o = t & (H_ - 1);
    const int which = t >> 7;
    const void* W = which ? Wt_w : Ws_w;
    float acc = ldin(which ? Wt_b : Ws_b, o, f32);
    for (int k = 0; k < H_; ++k)
        acc = fmaf(hg[k], ldin(W, (size_t)o * H_ + k, f32), acc);
    (which ? g_t_buf : g_s_buf)[(size_t)node * H_ + o] = acc;
}

// ---------------------------------------------------------------------------
// K3: nz-only scores + softmax + context + LayerNorm + combine -> h_new
// ---------------------------------------------------------------------------
__global__ __launch_bounds__(256) void k_attn(
    const void* adj, const void* vvec, const void* ln_g, const void* ln_b,
    const void* comb_w, const void* comb_b, void* out)
{
    const int f32 = g_isf32;
    __shared__ float s_i[H_];
    __shared__ float vv[H_];
    __shared__ float comb[2 * H_];   // [ h_lstm | h_att ]
    __shared__ u16 nzi[NZMAX];
    __shared__ float nzs[NZMAX];
    __shared__ int cnt;
    __shared__ float redbuf[256];
    __shared__ float bc[2];
    const int node = blockIdx.x;
    const int b = node / N_;
    const int t = threadIdx.x;

    if (t == 0) cnt = 0;
    if (t < H_) {
        s_i[t] = g_s_buf[(size_t)node * H_ + t];
        vv[t] = ldin(vvec, t, f32);
        comb[t] = g_h_lstm[(size_t)node * H_ + t];
    }
    __syncthreads();
    for (int j = t; j < N_; j += 256) {
        if (ldin(adj, (size_t)node * N_ + j, f32) != 0.f) {
            int p = atomicAdd(&cnt, 1);
            if (p < NZMAX) nzi[p] = (u16)j;
        }
    }
    __syncthreads();
    const int cn = min(cnt, NZMAX);

    // scores: one thread per neighbor, serial 128-dim dot
    for (int p = t; p < cn; p += 256) {
        const size_t base = ((size_t)b * N_ + nzi[p]) * H_;
        float a = 0.f;
        for (int k = 0; k < H_; ++k)
            a = fmaf(vv[k], tanhf(s_i[k] + g_t_buf[base + k]), a);
        nzs[p] = a;
    }
    __syncthreads();

    // serial softmax (thread 0); masked entries are exactly 0 after softmax
    if (t == 0) {
        float m = -1e30f;
        for (int p = 0; p < cn; ++p) m = fmaxf(m, nzs[p]);
        float ssum = 0.f;
        for (int p = 0; p < cn; ++p) { float e = expf(nzs[p] - m); nzs[p] = e; ssum += e; }
        bc[0] = 1.f / ssum;
    }
    __syncthreads();
    const float inv = bc[0];

    // context
    if (t < H_) {
        float acc = 0.f;
        for (int p = 0; p < cn; ++p)
            acc = fmaf(nzs[p], g_h_graph[((size_t)b * N_ + nzi[p]) * H_ + t], acc);
        redbuf[t] = acc * inv;
    }
    __syncthreads();

    // LayerNorm stats (thread 0, serial)
    if (t == 0) {
        float sm = 0.f, sq = 0.f;
        for (int k = 0; k < H_; ++k) { float xv = redbuf[k]; sm += xv; sq += xv * xv; }
        float mu = sm * (1.f / H_);
        float var = fmaxf(sq * (1.f / H_) - mu * mu, 0.f);
        bc[0] = mu;
        bc[1] = 1.f / sqrtf(var + 1e-5f);
    }
    __syncthreads();
    if (t < H_) {
        float xn = (redbuf[t] - bc[0]) * bc[1];
        comb[H_ + t] = ldin(ln_g, t, f32) * xn + ldin(ln_b, t, f32);
    }
    __syncthreads();

    // h_new[o] = comb_w[o, 0:256] . comb + comb_b[o]; k-range split over halves
    const int o = t & (H_ - 1);
    const int half = t >> 7;
    float acc = 0.f;
    for (int k = 0; k < H_; ++k)
        acc = fmaf(comb[half * H_ + k], ldin(comb_w, (size_t)o * (2 * H_) + half * H_ + k, f32), acc);
    redbuf[t] = acc;
    __syncthreads();
    if (t < H_)
        stout(out, (size_t)node * H_ + t, redbuf[t] + redbuf[t + H_] + ldin(comb_b, t, f32), f32);
}

// ---------------------------------------------------------------------------
extern "C" void kernel_launch(void* const* d_in, const int* in_sizes, int n_in,
                              void* d_out, int out_size, void* d_ws, size_t ws_size,
                              hipStream_t stream)
{
    (void)in_sizes; (void)n_in; (void)out_size; (void)d_ws; (void)ws_size;
    const void* x      = d_in[0];
    const void* adj    = d_in[1];
    const void* h      = d_in[2];
    const void* c      = d_in[3];
    const void* W_ih   = d_in[4];
    const void* W_hh   = d_in[5];
    const void* b_ih   = d_in[6];
    const void* b_hh   = d_in[7];
    const void* gc_w   = d_in[8];
    const void* gc_b   = d_in[9];
    const void* Ws_w   = d_in[10];
    const void* Ws_b   = d_in[11];
    const void* Wt_w   = d_in[12];
    const void* Wt_b   = d_in[13];
    const void* vvec   = d_in[14];
    const void* ln_g   = d_in[15];
    const void* ln_b   = d_in[16];
    const void* comb_w = d_in[17];
    const void* comb_b = d_in[18];

    k_probe<<<1, 1, 0, stream>>>(adj);
    k_lstm<<<NODES, 256, 0, stream>>>(x, h, c, W_ih, W_hh, b_ih, b_hh, gc_w, d_out);
    k_graph<<<NODES, 256, 0, stream>>>(adj, gc_b, Ws_w, Ws_b, Wt_w, Wt_b);
    k_attn<<<NODES, 256, 0, stream>>>(adj, vvec, ln_g, ln_b, comb_w, comb_b, d_out);
}

// Round 5
// 221.298 us; speedup vs baseline: 2.8816x; 2.8816x over previous
//
#include <hip/hip_runtime.h>

#define B_ 4
#define N_ 325
#define I_ 64
#define H_ 128
#define NODES (B_ * N_)
#define NZMAX 512

typedef unsigned short u16;
typedef unsigned int u32;

// Runtime input-dtype flag: 1 = fp32, 0 = bf16. Set by k_probe each launch.
__device__ int g_isf32;

// Module-scope scratch (allocated at .so load; fully rewritten every launch).
__device__ float g_h_lstm [NODES * H_];
__device__ float g_support[NODES * H_];
__device__ float g_h_graph[NODES * H_];
__device__ float g_s_buf  [NODES * H_];
__device__ float g_t_buf  [NODES * H_];

__device__ __forceinline__ float bf2f(u16 u) { return __uint_as_float(((u32)u) << 16); }
__device__ __forceinline__ float lo16(u32 u) { return __uint_as_float(u << 16); }
__device__ __forceinline__ float hi16(u32 u) { return __uint_as_float(u & 0xffff0000u); }
__device__ __forceinline__ u16 f2bf(float f) {
    u32 u = __float_as_uint(f);
    u += 0x7fffu + ((u >> 16) & 1u);   // round-to-nearest-even
    return (u16)(u >> 16);
}
__device__ __forceinline__ float ldin(const void* p, size_t i, int f32) {
    return f32 ? ((const float*)p)[i] : bf2f(((const u16*)p)[i]);
}
__device__ __forceinline__ void stout(void* p, size_t i, float v, int f32) {
    if (f32) ((float*)p)[i] = v; else ((u16*)p)[i] = f2bf(v);
}
__device__ __forceinline__ float fast_rcp(float x) { return __builtin_amdgcn_rcpf(x); }
__device__ __forceinline__ float sigm(float x) { return fast_rcp(1.f + __expf(-x)); }
__device__ __forceinline__ float tanh_f(float x) {
    x = fminf(15.f, fmaxf(-15.f, x));
    float e = __expf(2.f * x);
    return (e - 1.f) * fast_rcp(e + 1.f);
}

__device__ __forceinline__ void fma4f(const float* xx, float4 w, float& acc) {
    acc = fmaf(xx[0], w.x, acc); acc = fmaf(xx[1], w.y, acc);
    acc = fmaf(xx[2], w.z, acc); acc = fmaf(xx[3], w.w, acc);
}
__device__ __forceinline__ void fma4b(const float* xx, uint2 w, float& acc) {
    acc = fmaf(xx[0], lo16(w.x), acc); acc = fmaf(xx[1], hi16(w.x), acc);
    acc = fmaf(xx[2], lo16(w.y), acc); acc = fmaf(xx[3], hi16(w.y), acc);
}

// Dot of one weight row (n elems, n%4==0) against fp32 activations in LDS.
// fp32 path: float4 (all fp32 buffer sizes are 16B multiples -> 16B-aligned).
// bf16 path: uint2 = 4 bf16 (all bf16 buffer sizes are 8B multiples only).
template<int NCHUNK>
__device__ __forceinline__ float dotrow(const void* W, size_t row_elem_off,
                                        const float* xx, int f32) {
    float acc = 0.f;
    if (f32) {
        const float4* wr = reinterpret_cast<const float4*>((const float*)W + row_elem_off);
        #pragma unroll
        for (int k = 0; k < NCHUNK; ++k) { float4 w = wr[k]; fma4f(&xx[k * 4], w, acc); }
    } else {
        const uint2* wr = reinterpret_cast<const uint2*>((const u16*)W + row_elem_off);
        #pragma unroll
        for (int k = 0; k < NCHUNK; ++k) { uint2 w = wr[k]; fma4b(&xx[k * 4], w, acc); }
    }
    return acc;
}

// Probe adj[0,0] == 1.0 (self-loop guaranteed): bf16 puts 0x3F80 in the first
// 2 bytes; fp32 puts 0x0000 there (0x3F800000 little-endian).
__global__ void k_probe(const void* adj) {
    g_isf32 = ((((const u32*)adj)[0] & 0xFFFFu) != 0x3F80u) ? 1 : 0;
}

// ---------------------------------------------------------------------------
// K1: per-node LSTM cell + support = h_lstm @ gc_w.  One block per node.
// ---------------------------------------------------------------------------
__global__ __launch_bounds__(256) void k_lstm(
    const void* x, const void* h, const void* c,
    const void* W_ih, const void* W_hh, const void* b_ih, const void* b_hh,
    const void* gc_w, void* out)
{
    const int f32 = g_isf32;
    __shared__ float xh[I_ + H_];
    __shared__ float gates[4 * H_];
    __shared__ float hl[H_];
    __shared__ float spart[256];
    const int node = blockIdx.x;
    const int t = threadIdx.x;

    if (t < I_) xh[t] = ldin(x, (size_t)node * I_ + t, f32);
    if (t < H_) xh[I_ + t] = ldin(h, (size_t)node * H_ + t, f32);
    __syncthreads();

    #pragma unroll
    for (int gg = 0; gg < 2; ++gg) {
        const int g = t + gg * 256;
        float acc = ldin(b_ih, g, f32) + ldin(b_hh, g, f32);
        acc += dotrow<I_ / 4>(W_ih, (size_t)g * I_, xh, f32);
        acc += dotrow<H_ / 4>(W_hh, (size_t)g * H_, &xh[I_], f32);
        gates[g] = acc;
    }
    __syncthreads();

    if (t < H_) {
        float ig = gates[t], fg = gates[H_ + t], gv = gates[2 * H_ + t], og = gates[3 * H_ + t];
        float cl = sigm(fg) * ldin(c, (size_t)node * H_ + t, f32) + sigm(ig) * tanh_f(gv);
        float hv = sigm(og) * tanh_f(cl);
        stout(out, (size_t)(NODES * H_) + (size_t)node * H_ + t, cl, f32);  // c_lstm
        g_h_lstm[node * H_ + t] = hv;
        hl[t] = hv;
    }
    __syncthreads();

    // support[o] = sum_k hl[k] * gc_w[k][o]; lane-coalesced column walk,
    // k-range split across the two thread halves.
    const int o = t & (H_ - 1);
    const int half = t >> 7;
    float acc = 0.f;
    if (f32) {
        const float* G = (const float*)gc_w;
        for (int k = half * 64; k < half * 64 + 64; ++k)
            acc = fmaf(hl[k], G[(size_t)k * H_ + o], acc);
    } else {
        const u16* G = (const u16*)gc_w;
        for (int k = half * 64; k < half * 64 + 64; ++k)
            acc = fmaf(hl[k], bf2f(G[(size_t)k * H_ + o]), acc);
    }
    spart[t] = acc;
    __syncthreads();
    if (t < H_) g_support[node * H_ + t] = spart[t] + spart[t + H_];
}

// ---------------------------------------------------------------------------
// K2: sparse h_graph = adj @ support + gc_b ; s = h_graph @ Ws^T ; t = @ Wt^T
// ---------------------------------------------------------------------------
__global__ __launch_bounds__(256) void k_graph(
    const void* adj, const void* gc_b,
    const void* Ws_w, const void* Ws_b, const void* Wt_w, const void* Wt_b)
{
    const int f32 = g_isf32;
    __shared__ float hg[H_];
    __shared__ u16 nzi[NZMAX];
    __shared__ float nzv[NZMAX];
    __shared__ int cnt;
    const int node = blockIdx.x;
    const int b = node / N_;
    const int t = threadIdx.x;

    if (t == 0) cnt = 0;
    __syncthreads();
    for (int j = t; j < N_; j += 256) {
        float a = ldin(adj, (size_t)node * N_ + j, f32);
        if (a != 0.f) {
            int p = atomicAdd(&cnt, 1);
            if (p < NZMAX) { nzi[p] = (u16)j; nzv[p] = a; }
        }
    }
    __syncthreads();
    const int cn = min(cnt, NZMAX);

    if (t < H_) {
        float acc = ldin(gc_b, t, f32);
        for (int p = 0; p < cn; ++p)
            acc = fmaf(nzv[p], g_support[((size_t)b * N_ + nzi[p]) * H_ + t], acc);
        hg[t] = acc;
        g_h_graph[(size_t)node * H_ + t] = acc;
    }
    __syncthreads();

    // s (threads 0..127) and t (threads 128..255) projections: W[o][h] rows
    const int o = t & (H_ - 1);
    const int which = t >> 7;
    float acc = ldin(which ? Wt_b : Ws_b, o, f32);
    acc += dotrow<H_ / 4>(which ? Wt_w : Ws_w, (size_t)o * H_, hg, f32);
    (which ? g_t_buf : g_s_buf)[(size_t)node * H_ + o] = acc;
}

// ---------------------------------------------------------------------------
// K3: nz-only scores + softmax + context + LayerNorm + combine -> h_new
// ---------------------------------------------------------------------------
__global__ __launch_bounds__(256) void k_attn(
    const void* adj, const void* vvec, const void* ln_g, const void* ln_b,
    const void* comb_w, const void* comb_b, void* out)
{
    const int f32 = g_isf32;
    __shared__ float s_i[H_];
    __shared__ float vv[H_];
    __shared__ float comb[2 * H_];   // [ h_lstm | h_att ]
    __shared__ u16 nzi[NZMAX];
    __shared__ float nzs[NZMAX];
    __shared__ int cnt;
    __shared__ float redbuf[256];
    __shared__ float bc[2];
    const int node = blockIdx.x;
    const int b = node / N_;
    const int t = threadIdx.x;
    const int lane = t & 63;
    const int w = t >> 6;

    if (t == 0) cnt = 0;
    if (t < H_) {
        s_i[t] = g_s_buf[(size_t)node * H_ + t];
        vv[t] = ldin(vvec, t, f32);
        comb[t] = g_h_lstm[(size_t)node * H_ + t];
    }
    __syncthreads();
    for (int j = t; j < N_; j += 256) {
        if (ldin(adj, (size_t)node * N_ + j, f32) != 0.f) {
            int p = atomicAdd(&cnt, 1);
            if (p < NZMAX) nzi[p] = (u16)j;
        }
    }
    __syncthreads();
    const int cn = min(cnt, NZMAX);

    // scores: one wave per neighbor; lane l covers dims l and l+64
    const float v0 = vv[lane], v1 = vv[lane + 64];
    const float si0 = s_i[lane], si1 = s_i[lane + 64];
    for (int p = w; p < cn; p += 4) {
        const float* tj = g_t_buf + ((size_t)b * N_ + nzi[p]) * H_;
        float a = v0 * tanh_f(si0 + tj[lane]) + v1 * tanh_f(si1 + tj[lane + 64]);
        #pragma unroll
        for (int off = 32; off > 0; off >>= 1) a += __shfl_xor(a, off);
        if (lane == 0) nzs[p] = a;
    }
    __syncthreads();

    // softmax over nz scores (thread 0; cn ~ 17-30, masked entries exactly 0)
    if (t == 0) {
        float m = -1e30f;
        for (int p = 0; p < cn; ++p) m = fmaxf(m, nzs[p]);
        float ssum = 0.f;
        for (int p = 0; p < cn; ++p) { float e = __expf(nzs[p] - m); nzs[p] = e; ssum += e; }
        bc[0] = fast_rcp(ssum);
    }
    __syncthreads();
    const float inv = bc[0];

    // context (coalesced row reads of h_graph)
    if (t < H_) {
        float acc = 0.f;
        for (int p = 0; p < cn; ++p)
            acc = fmaf(nzs[p], g_h_graph[((size_t)b * N_ + nzi[p]) * H_ + t], acc);
        redbuf[t] = acc * inv;
    }
    __syncthreads();

    // LayerNorm stats (wave 0 shuffle reduce)
    if (w == 0) {
        float x0 = redbuf[lane], x1 = redbuf[lane + 64];
        float sm = x0 + x1;
        float sq = x0 * x0 + x1 * x1;
        #pragma unroll
        for (int off = 32; off > 0; off >>= 1) {
            sm += __shfl_xor(sm, off);
            sq += __shfl_xor(sq, off);
        }
        if (lane == 0) {
            float mu = sm * (1.f / H_);
            float var = fmaxf(sq * (1.f / H_) - mu * mu, 0.f);
            bc[0] = mu;
            bc[1] = __builtin_amdgcn_rsqf(var + 1e-5f);
        }
    }
    __syncthreads();
    if (t < H_) {
        float xn = (redbuf[t] - bc[0]) * bc[1];
        comb[H_ + t] = ldin(ln_g, t, f32) * xn + ldin(ln_b, t, f32);
    }
    __syncthreads();

    // h_new[o] = comb_w[o, 0:256] . comb + comb_b[o]; k-range split over halves
    const int o = t & (H_ - 1);
    const int half = t >> 7;
    float acc = dotrow<H_ / 4>(comb_w, (size_t)o * (2 * H_) + half * H_,
                               &comb[half * H_], f32);
    redbuf[t] = acc;
    __syncthreads();
    if (t < H_)
        stout(out, (size_t)node * H_ + t, redbuf[t] + redbuf[t + H_] + ldin(comb_b, t, f32), f32);
}

// ---------------------------------------------------------------------------
extern "C" void kernel_launch(void* const* d_in, const int* in_sizes, int n_in,
                              void* d_out, int out_size, void* d_ws, size_t ws_size,
                              hipStream_t stream)
{
    (void)in_sizes; (void)n_in; (void)out_size; (void)d_ws; (void)ws_size;
    const void* x      = d_in[0];
    const void* adj    = d_in[1];
    const void* h      = d_in[2];
    const void* c      = d_in[3];
    const void* W_ih   = d_in[4];
    const void* W_hh   = d_in[5];
    const void* b_ih   = d_in[6];
    const void* b_hh   = d_in[7];
    const void* gc_w   = d_in[8];
    const void* gc_b   = d_in[9];
    const void* Ws_w   = d_in[10];
    const void* Ws_b   = d_in[11];
    const void* Wt_w   = d_in[12];
    const void* Wt_b   = d_in[13];
    const void* vvec   = d_in[14];
    const void* ln_g   = d_in[15];
    const void* ln_b   = d_in[16];
    const void* comb_w = d_in[17];
    const void* comb_b = d_in[18];

    k_probe<<<1, 1, 0, stream>>>(adj);
    k_lstm<<<NODES, 256, 0, stream>>>(x, h, c, W_ih, W_hh, b_ih, b_hh, gc_w, d_out);
    k_graph<<<NODES, 256, 0, stream>>>(adj, gc_b, Ws_w, Ws_b, Wt_w, Wt_b);
    k_attn<<<NODES, 256, 0, stream>>>(adj, vvec, ln_g, ln_b, comb_w, comb_b, d_out);
}

// Round 6
// 181.725 us; speedup vs baseline: 3.5091x; 1.2178x over previous
//
#include <hip/hip_runtime.h>

#define B_ 4
#define N_ 325
#define I_ 64
#define H_ 128
#define NODES (B_ * N_)
#define NZMAX 512
#define NB 8                       // nodes per k_lstm block
#define GBLK ((NODES + NB - 1) / NB)

typedef unsigned short u16;
typedef unsigned int u32;

// Module-scope scratch (allocated at .so load; fully rewritten every launch).
__device__ float g_h_lstm [NODES * H_];
__device__ float g_support[NODES * H_];
__device__ float g_h_graph[NODES * H_];
__device__ float g_s_buf  [NODES * H_];
__device__ float g_t_buf  [NODES * H_];
__device__ u16   g_nz     [NODES * NZMAX];
__device__ int   g_nzc    [NODES];

__device__ __forceinline__ float bf2f(u16 u) { return __uint_as_float(((u32)u) << 16); }
__device__ __forceinline__ float lo16(u32 u) { return __uint_as_float(u << 16); }
__device__ __forceinline__ float hi16(u32 u) { return __uint_as_float(u & 0xffff0000u); }
__device__ __forceinline__ u16 f2bf(float f) {
    u32 u = __float_as_uint(f);
    u += 0x7fffu + ((u >> 16) & 1u);   // round-to-nearest-even
    return (u16)(u >> 16);
}
__device__ __forceinline__ float ldin(const void* p, size_t i, int f32) {
    return f32 ? ((const float*)p)[i] : bf2f(((const u16*)p)[i]);
}
__device__ __forceinline__ void stout(void* p, size_t i, float v, int f32) {
    if (f32) ((float*)p)[i] = v; else ((u16*)p)[i] = f2bf(v);
}
__device__ __forceinline__ float fast_rcp(float x) { return __builtin_amdgcn_rcpf(x); }
__device__ __forceinline__ float sigm(float x) { return fast_rcp(1.f + __expf(-x)); }
__device__ __forceinline__ float tanh_f(float x) {
    x = fminf(15.f, fmaxf(-15.f, x));
    float e = __expf(2.f * x);
    return (e - 1.f) * fast_rcp(e + 1.f);
}
// adj[0,0]==1.0 (self-loop): bf16 puts 0x3F80 in bytes 0-1; fp32 puts 0x0000.
__device__ __forceinline__ int probe_f32(const void* adj) {
    return ((((const u32*)adj)[0] & 0xFFFFu) != 0x3F80u) ? 1 : 0;
}

__device__ __forceinline__ void fma4f(const float* xx, float4 w, float& acc) {
    acc = fmaf(xx[0], w.x, acc); acc = fmaf(xx[1], w.y, acc);
    acc = fmaf(xx[2], w.z, acc); acc = fmaf(xx[3], w.w, acc);
}
__device__ __forceinline__ void fma4b(const float* xx, uint2 w, float& acc) {
    acc = fmaf(xx[0], lo16(w.x), acc); acc = fmaf(xx[1], hi16(w.x), acc);
    acc = fmaf(xx[2], lo16(w.y), acc); acc = fmaf(xx[3], hi16(w.y), acc);
}

// Row dot with 4-way split accumulators (breaks the serial FMA chain).
// fp32: float4 (fp32 tensors are 16B-multiples); bf16: uint2 only (8B align!).
template<int NCHUNK>
__device__ __forceinline__ float dotrow(const void* W, size_t row_elem_off,
                                        const float* xx, int f32) {
    float a0 = 0.f, a1 = 0.f, a2 = 0.f, a3 = 0.f;
    if (f32) {
        const float4* wr = reinterpret_cast<const float4*>((const float*)W + row_elem_off);
        #pragma unroll
        for (int k = 0; k < NCHUNK; ++k) {
            float4 w = wr[k];
            float* ap = (k & 1) ? ((k & 2) ? &a3 : &a1) : ((k & 2) ? &a2 : &a0);
            fma4f(&xx[k * 4], w, *ap);
        }
    } else {
        const uint2* wr = reinterpret_cast<const uint2*>((const u16*)W + row_elem_off);
        #pragma unroll
        for (int k = 0; k < NCHUNK; ++k) {
            uint2 w = wr[k];
            float* ap = (k & 1) ? ((k & 2) ? &a3 : &a1) : ((k & 2) ? &a2 : &a0);
            fma4b(&xx[k * 4], w, *ap);
        }
    }
    return (a0 + a1) + (a2 + a3);
}

// ---------------------------------------------------------------------------
// K1: 8 nodes/block LSTM + support GEMV. 512 threads; thread t owns gate row t.
// ---------------------------------------------------------------------------
__global__ __launch_bounds__(512) void k_lstm(
    const void* __restrict__ x, const void* __restrict__ h, const void* __restrict__ c,
    const void* __restrict__ W_ih, const void* __restrict__ W_hh,
    const void* __restrict__ b_ih, const void* __restrict__ b_hh,
    const void* __restrict__ gc_w, const void* __restrict__ adj, void* __restrict__ out)
{
    const int f32 = probe_f32(adj);
    __shared__ __align__(16) float xh[NB][I_ + H_];   // [n][0:64]=x, [64:192]=h
    __shared__ float gates[NB][4 * H_];               // 16 KB
    __shared__ __align__(16) float hl[NB][H_];
    const int node0 = blockIdx.x * NB;
    const int t = threadIdx.x;

    // --- A: stage activations (coalesced; zero-fill tail nodes) ---
    {
        int n = t >> 6, k = t & 63;                   // 512 == NB*64
        int node = node0 + n;
        xh[n][k] = (node < NODES) ? ldin(x, (size_t)node * I_ + k, f32) : 0.f;
    }
    for (int i = t; i < NB * H_; i += 512) {
        int n = i >> 7, k = i & 127;
        int node = node0 + n;
        xh[n][I_ + k] = (node < NODES) ? ldin(h, (size_t)node * H_ + k, f32) : 0.f;
    }
    __syncthreads();

    // --- B: gates[n][g] for 8 nodes, weights read once per block ---
    {
        const int g = t;
        float acc[NB];
        #pragma unroll
        for (int n = 0; n < NB; ++n) acc[n] = 0.f;
        if (f32) {
            const float4* wi = reinterpret_cast<const float4*>((const float*)W_ih + (size_t)g * I_);
            #pragma unroll
            for (int kc = 0; kc < I_ / 4; ++kc) {
                float4 w = wi[kc];
                #pragma unroll
                for (int n = 0; n < NB; ++n)
                    fma4f(&xh[n][kc * 4], w, acc[n]);
            }
            const float4* wh = reinterpret_cast<const float4*>((const float*)W_hh + (size_t)g * H_);
            #pragma unroll
            for (int kc = 0; kc < H_ / 4; ++kc) {
                float4 w = wh[kc];
                #pragma unroll
                for (int n = 0; n < NB; ++n)
                    fma4f(&xh[n][I_ + kc * 4], w, acc[n]);
            }
        } else {
            const uint2* wi = reinterpret_cast<const uint2*>((const u16*)W_ih + (size_t)g * I_);
            #pragma unroll
            for (int kc = 0; kc < I_ / 4; ++kc) {
                uint2 w = wi[kc];
                #pragma unroll
                for (int n = 0; n < NB; ++n)
                    fma4b(&xh[n][kc * 4], w, acc[n]);
            }
            const uint2* wh = reinterpret_cast<const uint2*>((const u16*)W_hh + (size_t)g * H_);
            #pragma unroll
            for (int kc = 0; kc < H_ / 4; ++kc) {
                uint2 w = wh[kc];
                #pragma unroll
                for (int n = 0; n < NB; ++n)
                    fma4b(&xh[n][I_ + kc * 4], w, acc[n]);
            }
        }
        const float bias = ldin(b_ih, g, f32) + ldin(b_hh, g, f32);
        #pragma unroll
        for (int n = 0; n < NB; ++n) gates[n][g] = acc[n] + bias;
    }
    __syncthreads();

    // --- C: nonlinearity; write c_lstm + h_lstm ---
    for (int e = t; e < NB * H_; e += 512) {
        int n = e >> 7, hh = e & 127;
        int node = node0 + n;
        float ig = gates[n][hh], fg = gates[n][H_ + hh];
        float gv = gates[n][2 * H_ + hh], og = gates[n][3 * H_ + hh];
        float cc = (node < NODES) ? ldin(c, (size_t)node * H_ + hh, f32) : 0.f;
        float cl = sigm(fg) * cc + sigm(ig) * tanh_f(gv);
        float hv = sigm(og) * tanh_f(cl);
        if (node < NODES) {
            stout(out, (size_t)(NODES * H_) + (size_t)node * H_ + hh, cl, f32);
            g_h_lstm[(size_t)node * H_ + hh] = hv;
        }
        hl[n][hh] = (node < NODES) ? hv : 0.f;
    }
    __syncthreads();

    // --- D: support[n][o] = hl[n] . gc_w[:,o]; thread does nodes nA, nA+4 ---
    {
        const int o = t & (H_ - 1);
        const int nA = t >> 7;             // 0..3
        const int nB2 = nA + 4;
        float aA = 0.f, aB = 0.f;
        if (f32) {
            const float* G = (const float*)gc_w;
            for (int k = 0; k < H_; ++k) {
                float gv = G[(size_t)k * H_ + o];
                aA = fmaf(hl[nA][k], gv, aA);
                aB = fmaf(hl[nB2][k], gv, aB);
            }
        } else {
            const u16* G = (const u16*)gc_w;
            for (int k = 0; k < H_; ++k) {
                float gv = bf2f(G[(size_t)k * H_ + o]);
                aA = fmaf(hl[nA][k], gv, aA);
                aB = fmaf(hl[nB2][k], gv, aB);
            }
        }
        int nodeA = node0 + nA, nodeB = node0 + nB2;
        if (nodeA < NODES) g_support[(size_t)nodeA * H_ + o] = aA;
        if (nodeB < NODES) g_support[(size_t)nodeB * H_ + o] = aB;
    }
}

// ---------------------------------------------------------------------------
// K2: nz compaction (stored for K3) + sparse h_graph + s/t projections
// ---------------------------------------------------------------------------
__global__ __launch_bounds__(256) void k_graph(
    const void* __restrict__ adj, const void* __restrict__ gc_b,
    const void* __restrict__ Ws_w, const void* __restrict__ Ws_b,
    const void* __restrict__ Wt_w, const void* __restrict__ Wt_b)
{
    const int f32 = probe_f32(adj);
    __shared__ __align__(16) float hg[H_];
    __shared__ u16 nzi[NZMAX];
    __shared__ float nzv[NZMAX];
    __shared__ float part[2][H_];
    __shared__ int cnt;
    const int node = blockIdx.x;
    const int b = node / N_;
    const int t = threadIdx.x;

    if (t == 0) cnt = 0;
    __syncthreads();
    for (int j = t; j < N_; j += 256) {
        float a = ldin(adj, (size_t)node * N_ + j, f32);
        if (a != 0.f) {
            int p = atomicAdd(&cnt, 1);
            if (p < NZMAX) { nzi[p] = (u16)j; nzv[p] = a; }
        }
    }
    __syncthreads();
    const int cn = min(cnt, NZMAX);
    if (t == 0) g_nzc[node] = cn;
    for (int p = t; p < cn; p += 256) g_nz[(size_t)node * NZMAX + p] = nzi[p];

    // h_graph: even/odd p split across thread halves (all 256 threads busy)
    const int o = t & (H_ - 1);
    const int half = t >> 7;
    float acc = 0.f;
    for (int p = half; p < cn; p += 2)
        acc = fmaf(nzv[p], g_support[((size_t)b * N_ + nzi[p]) * H_ + o], acc);
    part[half][o] = acc;
    __syncthreads();
    if (t < H_) {
        float v = part[0][t] + part[1][t] + ldin(gc_b, t, f32);
        hg[t] = v;
        g_h_graph[(size_t)node * H_ + t] = v;
    }
    __syncthreads();

    // s (threads 0..127) and t (threads 128..255) projections
    const int which = t >> 7;
    float acc2 = ldin(which ? Wt_b : Ws_b, o, f32);
    acc2 += dotrow<H_ / 4>(which ? Wt_w : Ws_w, (size_t)o * H_, hg, f32);
    (which ? g_t_buf : g_s_buf)[(size_t)node * H_ + o] = acc2;
}

// ---------------------------------------------------------------------------
// K3: nz-only scores + softmax + context + LayerNorm + combine -> h_new
// ---------------------------------------------------------------------------
__global__ __launch_bounds__(256) void k_attn(
    const void* __restrict__ adj, const void* __restrict__ vvec,
    const void* __restrict__ ln_g, const void* __restrict__ ln_b,
    const void* __restrict__ comb_w, const void* __restrict__ comb_b,
    void* __restrict__ out)
{
    const int f32 = probe_f32(adj);
    __shared__ float s_i[H_];
    __shared__ float vv[H_];
    __shared__ __align__(16) float comb[2 * H_];   // [ h_lstm | h_att ]
    __shared__ u16 nzi[NZMAX];
    __shared__ float nzs[NZMAX];
    __shared__ float part[2][H_];
    __shared__ float redbuf[256];
    __shared__ float bc[2];
    const int node = blockIdx.x;
    const int b = node / N_;
    const int t = threadIdx.x;
    const int lane = t & 63;
    const int w = t >> 6;

    const int cn = g_nzc[node];
    for (int p = t; p < cn; p += 256) nzi[p] = g_nz[(size_t)node * NZMAX + p];
    if (t < H_) {
        s_i[t] = g_s_buf[(size_t)node * H_ + t];
        vv[t] = ldin(vvec, t, f32);
        comb[t] = g_h_lstm[(size_t)node * H_ + t];
    }
    __syncthreads();

    // scores: 2 neighbors per wave (half-wave of 32 lanes each, 4 dims/lane)
    const int sl = lane & 31, hf = lane >> 5;
    const float v0 = vv[sl], v1 = vv[sl + 32], v2 = vv[sl + 64], v3 = vv[sl + 96];
    const float s0 = s_i[sl], s1 = s_i[sl + 32], s2 = s_i[sl + 64], s3 = s_i[sl + 96];
    for (int base = w * 2; base < cn; base += 8) {
        const int p = base + hf;
        float a = 0.f;
        if (p < cn) {
            const float* tj = g_t_buf + ((size_t)b * N_ + nzi[p]) * H_;
            a = v0 * tanh_f(s0 + tj[sl]) + v1 * tanh_f(s1 + tj[sl + 32])
              + v2 * tanh_f(s2 + tj[sl + 64]) + v3 * tanh_f(s3 + tj[sl + 96]);
        }
        a += __shfl_xor(a, 16); a += __shfl_xor(a, 8);
        a += __shfl_xor(a, 4);  a += __shfl_xor(a, 2); a += __shfl_xor(a, 1);
        if (sl == 0 && p < cn) nzs[p] = a;
    }
    __syncthreads();

    // softmax over nz scores (thread 0; cn ~ 17-30)
    if (t == 0) {
        float m = -1e30f;
        for (int p = 0; p < cn; ++p) m = fmaxf(m, nzs[p]);
        float ssum = 0.f;
        for (int p = 0; p < cn; ++p) { float e = __expf(nzs[p] - m); nzs[p] = e; ssum += e; }
        bc[0] = fast_rcp(ssum);
    }
    __syncthreads();
    const float inv = bc[0];

    // context: even/odd p split, all 256 threads
    const int o = t & (H_ - 1);
    const int half = t >> 7;
    {
        float acc = 0.f;
        for (int p = half; p < cn; p += 2)
            acc = fmaf(nzs[p], g_h_graph[((size_t)b * N_ + nzi[p]) * H_ + o], acc);
        part[half][o] = acc;
    }
    __syncthreads();
    if (t < H_) redbuf[t] = (part[0][t] + part[1][t]) * inv;
    __syncthreads();

    // LayerNorm stats (wave 0 shuffle reduce)
    if (w == 0) {
        float x0 = redbuf[lane], x1 = redbuf[lane + 64];
        float sm = x0 + x1;
        float sq = x0 * x0 + x1 * x1;
        #pragma unroll
        for (int off = 32; off > 0; off >>= 1) {
            sm += __shfl_xor(sm, off);
            sq += __shfl_xor(sq, off);
        }
        if (lane == 0) {
            float mu = sm * (1.f / H_);
            float var = fmaxf(sq * (1.f / H_) - mu * mu, 0.f);
            bc[0] = mu;
            bc[1] = __builtin_amdgcn_rsqf(var + 1e-5f);
        }
    }
    __syncthreads();
    if (t < H_) {
        float xn = (redbuf[t] - bc[0]) * bc[1];
        comb[H_ + t] = ldin(ln_g, t, f32) * xn + ldin(ln_b, t, f32);
    }
    __syncthreads();

    // h_new[o] = comb_w[o,:] . comb + comb_b[o]; k split over thread halves
    float acc2 = dotrow<H_ / 4>(comb_w, (size_t)o * (2 * H_) + (size_t)half * H_,
                                &comb[half * H_], f32);
    redbuf[t] = acc2;
    __syncthreads();
    if (t < H_)
        stout(out, (size_t)node * H_ + t,
              redbuf[t] + redbuf[t + H_] + ldin(comb_b, t, f32), f32);
}

// ---------------------------------------------------------------------------
extern "C" void kernel_launch(void* const* d_in, const int* in_sizes, int n_in,
                              void* d_out, int out_size, void* d_ws, size_t ws_size,
                              hipStream_t stream)
{
    (void)in_sizes; (void)n_in; (void)out_size; (void)d_ws; (void)ws_size;
    const void* x      = d_in[0];
    const void* adj    = d_in[1];
    const void* h      = d_in[2];
    const void* c      = d_in[3];
    const void* W_ih   = d_in[4];
    const void* W_hh   = d_in[5];
    const void* b_ih   = d_in[6];
    const void* b_hh   = d_in[7];
    const void* gc_w   = d_in[8];
    const void* gc_b   = d_in[9];
    const void* Ws_w   = d_in[10];
    const void* Ws_b   = d_in[11];
    const void* Wt_w   = d_in[12];
    const void* Wt_b   = d_in[13];
    const void* vvec   = d_in[14];
    const void* ln_g   = d_in[15];
    const void* ln_b   = d_in[16];
    const void* comb_w = d_in[17];
    const void* comb_b = d_in[18];

    k_lstm <<<GBLK, 512, 0, stream>>>(x, h, c, W_ih, W_hh, b_ih, b_hh, gc_w, adj, d_out);
    k_graph<<<NODES, 256, 0, stream>>>(adj, gc_b, Ws_w, Ws_b, Wt_w, Wt_b);
    k_attn <<<NODES, 256, 0, stream>>>(adj, vvec, ln_g, ln_b, comb_w, comb_b, d_out);
}

// Round 7
// 178.560 us; speedup vs baseline: 3.5714x; 1.0177x over previous
//
#include <hip/hip_runtime.h>

#define B_ 4
#define N_ 325
#define I_ 64
#define H_ 128
#define NODES (B_ * N_)
#define NZMAX 512
#define NB 4                        // nodes per block (1300 = 4*325, no tail)
#define GBLK (NODES / NB)           // 325 blocks for every kernel

typedef unsigned short u16;
typedef unsigned int u32;

// Module-scope scratch (allocated at .so load; fully rewritten every launch).
__device__ float g_h_lstm [NODES * H_];
__device__ float g_support[NODES * H_];
__device__ float g_h_graph[NODES * H_];
__device__ float g_s_buf  [NODES * H_];
__device__ float g_t_buf  [NODES * H_];
__device__ u16   g_nz     [NODES * NZMAX];
__device__ int   g_nzc    [NODES];

__device__ __forceinline__ float bf2f(u16 u) { return __uint_as_float(((u32)u) << 16); }
__device__ __forceinline__ float lo16(u32 u) { return __uint_as_float(u << 16); }
__device__ __forceinline__ float hi16(u32 u) { return __uint_as_float(u & 0xffff0000u); }
__device__ __forceinline__ u16 f2bf(float f) {
    u32 u = __float_as_uint(f);
    u += 0x7fffu + ((u >> 16) & 1u);   // round-to-nearest-even
    return (u16)(u >> 16);
}
__device__ __forceinline__ float ldin(const void* p, size_t i, int f32) {
    return f32 ? ((const float*)p)[i] : bf2f(((const u16*)p)[i]);
}
__device__ __forceinline__ void stout(void* p, size_t i, float v, int f32) {
    if (f32) ((float*)p)[i] = v; else ((u16*)p)[i] = f2bf(v);
}
__device__ __forceinline__ float fast_rcp(float x) { return __builtin_amdgcn_rcpf(x); }
__device__ __forceinline__ float sigm(float x) { return fast_rcp(1.f + __expf(-x)); }
__device__ __forceinline__ float tanh_f(float x) {
    x = fminf(15.f, fmaxf(-15.f, x));
    float e = __expf(2.f * x);
    return (e - 1.f) * fast_rcp(e + 1.f);
}
// adj[0,0]==1.0 (self-loop): bf16 puts 0x3F80 in bytes 0-1; fp32 puts 0x0000.
__device__ __forceinline__ int probe_f32(const void* adj) {
    return ((((const u32*)adj)[0] & 0xFFFFu) != 0x3F80u) ? 1 : 0;
}

__device__ __forceinline__ void fma4f(const float* xx, float4 w, float& acc) {
    acc = fmaf(xx[0], w.x, acc); acc = fmaf(xx[1], w.y, acc);
    acc = fmaf(xx[2], w.z, acc); acc = fmaf(xx[3], w.w, acc);
}
__device__ __forceinline__ void fma4b(const float* xx, uint2 w, float& acc) {
    acc = fmaf(xx[0], lo16(w.x), acc); acc = fmaf(xx[1], hi16(w.x), acc);
    acc = fmaf(xx[2], lo16(w.y), acc); acc = fmaf(xx[3], hi16(w.y), acc);
}

// ---------------------------------------------------------------------------
// K1: 4 nodes/block LSTM + support GEMV. 512 threads; thread t owns gate row t.
// ---------------------------------------------------------------------------
__global__ __launch_bounds__(512) void k_lstm(
    const void* __restrict__ x, const void* __restrict__ h, const void* __restrict__ c,
    const void* __restrict__ W_ih, const void* __restrict__ W_hh,
    const void* __restrict__ b_ih, const void* __restrict__ b_hh,
    const void* __restrict__ gc_w, const void* __restrict__ adj, void* __restrict__ out)
{
    const int f32 = probe_f32(adj);
    __shared__ __align__(16) float xh[NB][I_ + H_];   // [n][0:64]=x, [64:192]=h
    __shared__ float gates[NB][4 * H_];
    __shared__ __align__(16) float hl[NB][H_];
    const int node0 = blockIdx.x * NB;
    const int t = threadIdx.x;

    // --- A: stage activations (coalesced) ---
    if (t < NB * I_) {                          // 256 elems of x
        int n = t >> 6, k = t & 63;
        xh[n][k] = ldin(x, (size_t)(node0 + n) * I_ + k, f32);
    }
    {                                           // 512 elems of h
        int n = t >> 7, k = t & 127;
        xh[n][I_ + k] = ldin(h, (size_t)(node0 + n) * H_ + k, f32);
    }
    __syncthreads();

    // --- B: gates for 4 nodes; weight row read once per thread ---
    {
        const int g = t;
        float acc[NB] = {0.f, 0.f, 0.f, 0.f};
        if (f32) {
            const float4* wi = reinterpret_cast<const float4*>((const float*)W_ih + (size_t)g * I_);
            #pragma unroll
            for (int kc = 0; kc < I_ / 4; ++kc) {
                float4 w = wi[kc];
                #pragma unroll
                for (int n = 0; n < NB; ++n) fma4f(&xh[n][kc * 4], w, acc[n]);
            }
            const float4* wh = reinterpret_cast<const float4*>((const float*)W_hh + (size_t)g * H_);
            #pragma unroll
            for (int kc = 0; kc < H_ / 4; ++kc) {
                float4 w = wh[kc];
                #pragma unroll
                for (int n = 0; n < NB; ++n) fma4f(&xh[n][I_ + kc * 4], w, acc[n]);
            }
        } else {
            const uint2* wi = reinterpret_cast<const uint2*>((const u16*)W_ih + (size_t)g * I_);
            #pragma unroll
            for (int kc = 0; kc < I_ / 4; ++kc) {
                uint2 w = wi[kc];
                #pragma unroll
                for (int n = 0; n < NB; ++n) fma4b(&xh[n][kc * 4], w, acc[n]);
            }
            const uint2* wh = reinterpret_cast<const uint2*>((const u16*)W_hh + (size_t)g * H_);
            #pragma unroll
            for (int kc = 0; kc < H_ / 4; ++kc) {
                uint2 w = wh[kc];
                #pragma unroll
                for (int n = 0; n < NB; ++n) fma4b(&xh[n][I_ + kc * 4], w, acc[n]);
            }
        }
        const float bias = ldin(b_ih, g, f32) + ldin(b_hh, g, f32);
        #pragma unroll
        for (int n = 0; n < NB; ++n) gates[n][g] = acc[n] + bias;
    }
    __syncthreads();

    // --- C: nonlinearity; write c_lstm + h_lstm ---
    {
        int n = t >> 7, hh = t & 127;
        int node = node0 + n;
        float ig = gates[n][hh], fg = gates[n][H_ + hh];
        float gv = gates[n][2 * H_ + hh], og = gates[n][3 * H_ + hh];
        float cl = sigm(fg) * ldin(c, (size_t)node * H_ + hh, f32) + sigm(ig) * tanh_f(gv);
        float hv = sigm(og) * tanh_f(cl);
        stout(out, (size_t)(NODES * H_) + (size_t)node * H_ + hh, cl, f32);
        g_h_lstm[(size_t)node * H_ + hh] = hv;
        hl[n][hh] = hv;
    }
    __syncthreads();

    // --- D: support[n][o] = hl[n] . gc_w[:,o]; lane-coalesced column walk ---
    {
        const int o = t & (H_ - 1);
        const int n = t >> 7;
        float acc = 0.f;
        if (f32) {
            const float* G = (const float*)gc_w;
            for (int k = 0; k < H_; ++k)
                acc = fmaf(hl[n][k], G[(size_t)k * H_ + o], acc);
        } else {
            const u16* G = (const u16*)gc_w;
            for (int k = 0; k < H_; ++k)
                acc = fmaf(hl[n][k], bf2f(G[(size_t)k * H_ + o]), acc);
        }
        g_support[(size_t)(node0 + n) * H_ + o] = acc;
    }
}

// ---------------------------------------------------------------------------
// K2: 4 nodes/block: nz compaction + sparse h_graph + s/t projections
// ---------------------------------------------------------------------------
__global__ __launch_bounds__(256) void k_graph(
    const void* __restrict__ adj, const void* __restrict__ gc_b,
    const void* __restrict__ Ws_w, const void* __restrict__ Ws_b,
    const void* __restrict__ Wt_w, const void* __restrict__ Wt_b)
{
    const int f32 = probe_f32(adj);
    __shared__ __align__(16) float hg[NB][H_];
    __shared__ u16 nzi[NB][NZMAX];
    __shared__ float nzv[NB][NZMAX];
    __shared__ int cnt[NB];
    const int node0 = blockIdx.x * NB;
    const int t = threadIdx.x;
    const int w = t >> 6, lane = t & 63;

    if (lane == 0) cnt[w] = 0;
    __syncthreads();
    // wave w compacts row node0+w
    for (int j = lane; j < N_; j += 64) {
        float a = ldin(adj, (size_t)(node0 + w) * N_ + j, f32);
        if (a != 0.f) {
            int p = atomicAdd(&cnt[w], 1);
            if (p < NZMAX) { nzi[w][p] = (u16)j; nzv[w][p] = a; }
        }
    }
    __syncthreads();
    if (t < NB) g_nzc[node0 + t] = min(cnt[t], NZMAX);
    #pragma unroll
    for (int n = 0; n < NB; ++n) {
        const int cnn = min(cnt[n], NZMAX);
        for (int p = t; p < cnn; p += 256) g_nz[(size_t)(node0 + n) * NZMAX + p] = nzi[n][p];
    }

    // h_graph: 2 passes of (2 nodes x 128 outputs)
    const int o = t & (H_ - 1);
    #pragma unroll
    for (int pass = 0; pass < 2; ++pass) {
        const int n = (t >> 7) + 2 * pass;
        const int node = node0 + n;
        const int bn = node / N_;
        const int cnn = min(cnt[n], NZMAX);
        float acc = ldin(gc_b, o, f32);
        for (int p = 0; p < cnn; ++p)
            acc = fmaf(nzv[n][p], g_support[((size_t)bn * N_ + nzi[n][p]) * H_ + o], acc);
        hg[n][o] = acc;
        g_h_graph[(size_t)node * H_ + o] = acc;
    }
    __syncthreads();

    // s (threads 0..127) / t (threads 128..255) projections, 4 nodes amortized
    {
        const int which = t >> 7;
        const void* W = which ? Wt_w : Ws_w;
        const float bias = ldin(which ? Wt_b : Ws_b, o, f32);
        float acc[NB] = {0.f, 0.f, 0.f, 0.f};
        if (f32) {
            const float4* wr = reinterpret_cast<const float4*>((const float*)W + (size_t)o * H_);
            #pragma unroll
            for (int kc = 0; kc < H_ / 4; ++kc) {
                float4 wv = wr[kc];
                #pragma unroll
                for (int n = 0; n < NB; ++n) fma4f(&hg[n][kc * 4], wv, acc[n]);
            }
        } else {
            const uint2* wr = reinterpret_cast<const uint2*>((const u16*)W + (size_t)o * H_);
            #pragma unroll
            for (int kc = 0; kc < H_ / 4; ++kc) {
                uint2 wv = wr[kc];
                #pragma unroll
                for (int n = 0; n < NB; ++n) fma4b(&hg[n][kc * 4], wv, acc[n]);
            }
        }
        float* dst = which ? g_t_buf : g_s_buf;
        #pragma unroll
        for (int n = 0; n < NB; ++n)
            dst[(size_t)(node0 + n) * H_ + o] = acc[n] + bias;
    }
}

// ---------------------------------------------------------------------------
// K3: 4 nodes/block: scores + softmax + context + LayerNorm + combine
// ---------------------------------------------------------------------------
__global__ __launch_bounds__(256) void k_attn(
    const void* __restrict__ adj, const void* __restrict__ vvec,
    const void* __restrict__ ln_g, const void* __restrict__ ln_b,
    const void* __restrict__ comb_w, const void* __restrict__ comb_b,
    void* __restrict__ out)
{
    const int f32 = probe_f32(adj);
    __shared__ float s_i[NB][H_];
    __shared__ float vv[H_];
    __shared__ __align__(16) float comb[NB][2 * H_];   // [ h_lstm | h_att ]
    __shared__ u16 nzi[NB][NZMAX];
    __shared__ float nzs[NB][NZMAX];
    __shared__ float red[NB][H_];
    __shared__ float part[2][NB][H_];
    __shared__ float bc[NB][2];
    __shared__ int cnt4[NB];
    const int node0 = blockIdx.x * NB;
    const int t = threadIdx.x;
    const int w = t >> 6, lane = t & 63;

    if (t < NB) cnt4[t] = g_nzc[node0 + t];
    if (t < H_) vv[t] = ldin(vvec, t, f32);
    #pragma unroll
    for (int pass = 0; pass < 2; ++pass) {
        int n = (t >> 7) + 2 * pass, k = t & 127;
        s_i[n][k] = g_s_buf[(size_t)(node0 + n) * H_ + k];
        comb[n][k] = g_h_lstm[(size_t)(node0 + n) * H_ + k];
    }
    __syncthreads();
    #pragma unroll
    for (int n = 0; n < NB; ++n)
        for (int p = t; p < cnt4[n]; p += 256) nzi[n][p] = g_nz[(size_t)(node0 + n) * NZMAX + p];
    __syncthreads();

    // scores: wave w owns node w; lane covers dims lane, lane+64
    {
        const int bn = (node0 + w) / N_;
        const int cn = cnt4[w];
        const float v0 = vv[lane], v1 = vv[lane + 64];
        const float si0 = s_i[w][lane], si1 = s_i[w][lane + 64];
        for (int p = 0; p < cn; ++p) {
            const float* tj = g_t_buf + ((size_t)bn * N_ + nzi[w][p]) * H_;
            float a = v0 * tanh_f(si0 + tj[lane]) + v1 * tanh_f(si1 + tj[lane + 64]);
            #pragma unroll
            for (int off = 32; off > 0; off >>= 1) a += __shfl_xor(a, off);
            if (lane == 0) nzs[w][p] = a;
        }
    }
    __syncthreads();

    // softmax: threads 0..3, node t each (serial over ~17-30 entries)
    if (t < NB) {
        const int cn = cnt4[t];
        float m = -1e30f;
        for (int p = 0; p < cn; ++p) m = fmaxf(m, nzs[t][p]);
        float ssum = 0.f;
        for (int p = 0; p < cn; ++p) { float e = __expf(nzs[t][p] - m); nzs[t][p] = e; ssum += e; }
        bc[t][0] = fast_rcp(ssum);
    }
    __syncthreads();

    // context: 2 passes of (2 nodes x 128 outputs)
    const int o = t & (H_ - 1);
    #pragma unroll
    for (int pass = 0; pass < 2; ++pass) {
        const int n = (t >> 7) + 2 * pass;
        const int bn = (node0 + n) / N_;
        const int cn = cnt4[n];
        float acc = 0.f;
        for (int p = 0; p < cn; ++p)
            acc = fmaf(nzs[n][p], g_h_graph[((size_t)bn * N_ + nzi[n][p]) * H_ + o], acc);
        red[n][o] = acc * bc[n][0];
    }
    __syncthreads();

    // LayerNorm stats: wave w owns node w
    {
        float x0 = red[w][lane], x1 = red[w][lane + 64];
        float sm = x0 + x1, sq = x0 * x0 + x1 * x1;
        #pragma unroll
        for (int off = 32; off > 0; off >>= 1) {
            sm += __shfl_xor(sm, off);
            sq += __shfl_xor(sq, off);
        }
        if (lane == 0) {
            float mu = sm * (1.f / H_);
            float var = fmaxf(sq * (1.f / H_) - mu * mu, 0.f);
            bc[w][0] = mu;
            bc[w][1] = __builtin_amdgcn_rsqf(var + 1e-5f);
        }
    }
    __syncthreads();
    #pragma unroll
    for (int pass = 0; pass < 2; ++pass) {
        int n = (t >> 7) + 2 * pass, k = t & 127;
        float xn = (red[n][k] - bc[n][0]) * bc[n][1];
        comb[n][H_ + k] = ldin(ln_g, k, f32) * xn + ldin(ln_b, k, f32);
    }
    __syncthreads();

    // combine GEMV: thread owns (o, half); 4 nodes amortize the weight row
    {
        const int half = t >> 7;
        float acc[NB] = {0.f, 0.f, 0.f, 0.f};
        if (f32) {
            const float4* wr = reinterpret_cast<const float4*>(
                (const float*)comb_w + (size_t)o * (2 * H_) + (size_t)half * H_);
            #pragma unroll
            for (int kc = 0; kc < H_ / 4; ++kc) {
                float4 wv = wr[kc];
                #pragma unroll
                for (int n = 0; n < NB; ++n) fma4f(&comb[n][half * H_ + kc * 4], wv, acc[n]);
            }
        } else {
            const uint2* wr = reinterpret_cast<const uint2*>(
                (const u16*)comb_w + (size_t)o * (2 * H_) + (size_t)half * H_);
            #pragma unroll
            for (int kc = 0; kc < H_ / 4; ++kc) {
                uint2 wv = wr[kc];
                #pragma unroll
                for (int n = 0; n < NB; ++n) fma4b(&comb[n][half * H_ + kc * 4], wv, acc[n]);
            }
        }
        #pragma unroll
        for (int n = 0; n < NB; ++n) part[half][n][o] = acc[n];
    }
    __syncthreads();
    #pragma unroll
    for (int pass = 0; pass < 2; ++pass) {
        int n = (t >> 7) + 2 * pass, k = t & 127;
        stout(out, (size_t)(node0 + n) * H_ + k,
              part[0][n][k] + part[1][n][k] + ldin(comb_b, k, f32), f32);
    }
}

// ---------------------------------------------------------------------------
extern "C" void kernel_launch(void* const* d_in, const int* in_sizes, int n_in,
                              void* d_out, int out_size, void* d_ws, size_t ws_size,
                              hipStream_t stream)
{
    (void)in_sizes; (void)n_in; (void)out_size; (void)d_ws; (void)ws_size;
    const void* x      = d_in[0];
    const void* adj    = d_in[1];
    const void* h      = d_in[2];
    const void* c      = d_in[3];
    const void* W_ih   = d_in[4];
    const void* W_hh   = d_in[5];
    const void* b_ih   = d_in[6];
    const void* b_hh   = d_in[7];
    const void* gc_w   = d_in[8];
    const void* gc_b   = d_in[9];
    const void* Ws_w   = d_in[10];
    const void* Ws_b   = d_in[11];
    const void* Wt_w   = d_in[12];
    const void* Wt_b   = d_in[13];
    const void* vvec   = d_in[14];
    const void* ln_g   = d_in[15];
    const void* ln_b   = d_in[16];
    const void* comb_w = d_in[17];
    const void* comb_b = d_in[18];

    k_lstm <<<GBLK, 512, 0, stream>>>(x, h, c, W_ih, W_hh, b_ih, b_hh, gc_w, adj, d_out);
    k_graph<<<GBLK, 256, 0, stream>>>(adj, gc_b, Ws_w, Ws_b, Wt_w, Wt_b);
    k_attn <<<GBLK, 256, 0, stream>>>(adj, vvec, ln_g, ln_b, comb_w, comb_b, d_out);
}